// Round 1
// baseline (1900.633 us; speedup 1.0000x reference)
//
#include <hip/hip_runtime.h>
#include <math.h>

#define NB 4
#define NH 48
#define NW 48
#define NC 192
#define NL 2304           // NH*NW
#define NM 9216           // NB*NL
#define DIN 384
#define XD 44             // DT_RANK + 2*D_STATE
#define DTR 12

// ---------------- generic f32 GEMM: C[m,n] = sum_k A[m,k]*Wt[n,k] ----------------
#define BM 128
#define BN 64
#define BK 16
__global__ __launch_bounds__(256) void sgemm_nt(
    const float* __restrict__ A, int lda,
    const float* __restrict__ Wt,
    float* __restrict__ Cm, int ldc,
    int N, int K, int zA, int zW, int zC)
{
  A  += (size_t)blockIdx.z * zA;
  Wt += (size_t)blockIdx.z * zW;
  Cm += (size_t)blockIdx.z * zC;
  __shared__ float As[BK][BM+4];
  __shared__ float Bs[BK][BN+4];
  const int tid = threadIdx.x;
  const int bm = blockIdx.y * BM;
  const int bn = blockIdx.x * BN;
  const int ty = tid >> 4, tx = tid & 15;
  float acc[8][4];
  #pragma unroll
  for (int r = 0; r < 8; ++r)
    #pragma unroll
    for (int c = 0; c < 4; ++c) acc[r][c] = 0.f;

  for (int k0 = 0; k0 < K; k0 += BK) {
    #pragma unroll
    for (int i = 0; i < 2; ++i) {
      int e = tid + i*256;
      int row = e >> 2;
      int k4 = (e & 3) << 2;
      float4 v = *(const float4*)(A + (size_t)(bm+row)*lda + k0 + k4);
      As[k4+0][row]=v.x; As[k4+1][row]=v.y; As[k4+2][row]=v.z; As[k4+3][row]=v.w;
    }
    {
      int n = tid >> 2;
      int k4 = (tid & 3) << 2;
      float4 v = make_float4(0.f,0.f,0.f,0.f);
      if (bn + n < N) v = *(const float4*)(Wt + (size_t)(bn+n)*K + k0 + k4);
      Bs[k4+0][n]=v.x; Bs[k4+1][n]=v.y; Bs[k4+2][n]=v.z; Bs[k4+3][n]=v.w;
    }
    __syncthreads();
    #pragma unroll
    for (int k = 0; k < BK; ++k) {
      float a[8], bb[4];
      #pragma unroll
      for (int r = 0; r < 8; ++r) a[r] = As[k][ty*8+r];
      #pragma unroll
      for (int c = 0; c < 4; ++c) bb[c] = Bs[k][tx*4+c];
      #pragma unroll
      for (int r = 0; r < 8; ++r)
        #pragma unroll
        for (int c = 0; c < 4; ++c) acc[r][c] = fmaf(a[r], bb[c], acc[r][c]);
    }
    __syncthreads();
  }
  #pragma unroll
  for (int r = 0; r < 8; ++r) {
    int m = bm + ty*8 + r;
    #pragma unroll
    for (int c = 0; c < 4; ++c) {
      int n = bn + tx*4 + c;
      if (n < N) Cm[(size_t)m*ldc + n] = acc[r][c];
    }
  }
}

// ---------------- transpose x (B,H,W,C) -> u1 (B, W*H, C) ----------------
__global__ __launch_bounds__(256) void transpose_in(const float* __restrict__ x, float* __restrict__ u1)
{
  int idx = blockIdx.x*256 + threadIdx.x;   // < NB*NL*NC
  int c = idx % NC;
  int rr = idx / NC;
  int s1 = rr % NL;        // w*NH + h
  int b  = rr / NL;
  int hh = s1 % NH;
  int ww = s1 / NH;
  u1[idx] = x[(((size_t)b*NH + hh)*NW + ww)*NC + c];
}

// ---------------- depthwise causal conv (both dirs) + silu ----------------
// xz (B,L,1536): cols [0,384) xh_f, [384,768) z_f, [768,1152) xh_r, [1152,1536) z_r
// xc (B,L,768): cols [0,384) fwd, [384,768) rev
__global__ __launch_bounds__(256) void conv_silu(
    const float* __restrict__ xz, const float* __restrict__ cw, const float* __restrict__ cb,
    float* __restrict__ xc, int pi)
{
  int idx = blockIdx.x*256 + threadIdx.x;   // < NB*NL*768
  int d2 = idx % 768;
  int r  = idx / 768;      // b*NL + s
  int s  = r % NL;
  int dir = d2 / 384;
  int d = d2 - dir*384;
  int p = pi + dir;
  const float* w = cw + ((size_t)p*DIN + d)*3;
  float acc = cb[p*DIN + d];
  const float* col = xz + (size_t)(r - s)*1536 + (dir*768 + d);  // base row of this b
  if (dir == 0) {
    if (s >= 2) acc = fmaf(w[0], col[(size_t)(s-2)*1536], acc);
    if (s >= 1) acc = fmaf(w[1], col[(size_t)(s-1)*1536], acc);
    acc = fmaf(w[2], col[(size_t)s*1536], acc);
  } else {
    if (s+2 < NL) acc = fmaf(w[0], col[(size_t)(s+2)*1536], acc);
    if (s+1 < NL) acc = fmaf(w[1], col[(size_t)(s+1)*1536], acc);
    acc = fmaf(w[2], col[(size_t)s*1536], acc);
  }
  float sg = 1.f / (1.f + __expf(-acc));
  xc[idx] = acc * sg;
}

// ---------------- dt_proj + softplus ----------------
// xdbl (B,L,88): [0,12) dt, [12,28) B, [28,44) C for dir0, +44 for dir1
__global__ __launch_bounds__(256) void dt_softplus(
    const float* __restrict__ xdbl, const float* __restrict__ dtw, const float* __restrict__ dtb,
    float* __restrict__ delta, int pi)
{
  int idx = blockIdx.x*256 + threadIdx.x;   // < NB*NL*768
  int d2 = idx % 768;
  size_t r = idx / 768;
  int dir = d2 / 384;
  int d = d2 - dir*384;
  int p = pi + dir;
  const float* v = xdbl + r*88 + dir*XD;
  const float* w = dtw + ((size_t)p*DIN + d)*DTR;
  float acc = dtb[p*DIN + d];
  #pragma unroll
  for (int k = 0; k < DTR; ++k) acc = fmaf(v[k], w[k], acc);
  delta[idx] = fmaxf(acc, 0.f) + log1pf(__expf(-fabsf(acc)));
}

// ---------------- selective scan (both dirs), writes g in-place over delta ----------------
#define SCT 64
#define SCAN_STEP(T_) do {                                            \
    float dlt = sdelta[T_][cl];                                        \
    float xcv = sxc[T_][cl];                                           \
    float bv = sbc[T_][2*n], cv = sbc[T_][2*n+1];                      \
    float a = __expf(dlt * Areg);                                      \
    h = fmaf(a, h, dlt * xcv * bv);                                    \
    float ps = h * cv;                                                 \
    ps += __shfl_xor(ps, 1);                                           \
    ps += __shfl_xor(ps, 2);                                           \
    ps += __shfl_xor(ps, 4);                                           \
    ps += __shfl_xor(ps, 8);                                           \
    if (n == 0) {                                                      \
      float y = ps + xcv * Dreg;                                       \
      float zv = szf[T_][cl];                                          \
      sg[T_][cl] = y * (zv / (1.f + __expf(-zv)));                     \
    }                                                                  \
  } while (0)

__global__ __launch_bounds__(256) void scan_kernel(
    float* deltag, const float* __restrict__ xc, const float* __restrict__ xz,
    const float* __restrict__ xdbl, const float* __restrict__ alog,
    const float* __restrict__ dvec, int pi)
{
  const int bx = blockIdx.x;         // 192 blocks: b(4) x dir(2) x 24 channel-groups
  const int b = bx / 48;
  const int rem = bx % 48;
  const int dir = rem / 24;
  const int d0 = (rem % 24) * 16;
  const int tid = threadIdx.x;
  const int cl = tid >> 4;           // channel local 0..15
  const int n  = tid & 15;           // state index
  const int d = d0 + cl;
  const int p = pi + dir;
  const float Areg = -__expf(alog[((size_t)p*DIN + d)*16 + n]);
  const float Dreg = dvec[p*DIN + d];

  __shared__ float sdelta[SCT][16];
  __shared__ float sxc[SCT][16];
  __shared__ float szf[SCT][16];
  __shared__ float sbc[SCT][32];
  __shared__ float sg[SCT][16];

  const size_t rb = (size_t)b * NL;
  float h = 0.f;
  for (int ci = 0; ci < NL/SCT; ++ci) {
    const int c0 = dir ? (NL - SCT - ci*SCT) : ci*SCT;
    #pragma unroll
    for (int j = 0; j < 4; ++j) {
      int e = tid + j*256;
      int t = e >> 4, c = e & 15;
      size_t row = rb + c0 + t;
      sdelta[t][c] = deltag[row*768 + dir*384 + d0 + c];
      sxc[t][c]    = xc[row*768 + dir*384 + d0 + c];
      szf[t][c]    = xz[row*1536 + dir*768 + 384 + d0 + c];
    }
    #pragma unroll
    for (int j = 0; j < 8; ++j) {
      int e = tid + j*256;
      int t = e >> 5, q = e & 31;
      int nn = q >> 1;
      sbc[t][q] = xdbl[(rb + c0 + t)*88 + dir*XD + 12 + ((q & 1) << 4) + nn];
    }
    __syncthreads();
    if (dir == 0) {
      #pragma unroll 4
      for (int t = 0; t < SCT; ++t) { SCAN_STEP(t); }
    } else {
      #pragma unroll 4
      for (int t = SCT-1; t >= 0; --t) { SCAN_STEP(t); }
    }
    __syncthreads();
    #pragma unroll
    for (int j = 0; j < 4; ++j) {
      int e = tid + j*256;
      int t = e >> 4, c = e & 15;
      deltag[(rb + c0 + t)*768 + dir*384 + d0 + c] = sg[t][c];
    }
  }
}

// ---------------- LayerNorm + residual + transpose back (after layer 1) ----------------
__device__ inline float wave_sum(float v) {
  #pragma unroll
  for (int m = 1; m < 64; m <<= 1) v += __shfl_xor(v, m);
  return v;
}
__global__ __launch_bounds__(192) void ln_res(
    const float* __restrict__ ob0, const float* __restrict__ ob1,
    const float* __restrict__ x, const float* __restrict__ nw, const float* __restrict__ nb2,
    float* __restrict__ u2)
{
  int pb = blockIdx.x;   // b*NL + h*NW + w
  int c = threadIdx.x;
  int b = pb / NL;
  int hw = pb % NL;
  int hh = hw / NW;
  int ww = hw % NW;
  int s1 = ww*NH + hh;   // position in the W-major layer-1 sequence
  float v = ob0[((size_t)b*NL + s1)*NC + c] + ob1[((size_t)b*NL + (NL-1-s1))*NC + c];
  __shared__ float red[6];
  float sv = wave_sum(v);
  int wid = c >> 6;
  if ((c & 63) == 0) red[wid] = sv;
  __syncthreads();
  float mean = (red[0]+red[1]+red[2]) * (1.f/NC);
  float dv = v - mean;
  float s2 = wave_sum(dv*dv);
  if ((c & 63) == 0) red[3+wid] = s2;
  __syncthreads();
  float var = (red[3]+red[4]+red[5]) * (1.f/NC);
  u2[(size_t)pb*NC + c] = dv * rsqrtf(var + 1e-5f) * nw[c] + nb2[c] + x[(size_t)pb*NC + c];
}

// ---------------- final add with flip (layer 2 output) ----------------
__global__ __launch_bounds__(256) void add_flip(
    const float* __restrict__ ob0, const float* __restrict__ ob1, float* __restrict__ out)
{
  int idx = blockIdx.x*256 + threadIdx.x;   // < NB*NL*NC
  int c = idx % NC;
  int rr = idx / NC;
  int t = rr % NL;
  int b = rr / NL;
  out[idx] = ob0[idx] + ob1[((size_t)b*NL + (NL-1-t))*NC + c];
}

extern "C" void kernel_launch(void* const* d_in, const int* in_sizes, int n_in,
                              void* d_out, int out_size, void* d_ws, size_t ws_size,
                              hipStream_t stream)
{
  const float* x    = (const float*)d_in[0];
  const float* inw  = (const float*)d_in[1];
  const float* cw   = (const float*)d_in[2];
  const float* cb   = (const float*)d_in[3];
  const float* xpw  = (const float*)d_in[4];
  const float* dtw  = (const float*)d_in[5];
  const float* dtb  = (const float*)d_in[6];
  const float* alog = (const float*)d_in[7];
  const float* dvec = (const float*)d_in[8];
  const float* outw = (const float*)d_in[9];
  const float* nw   = (const float*)d_in[10];
  const float* nb   = (const float*)d_in[11];
  float* outp = (float*)d_out;
  (void)in_sizes; (void)n_in; (void)out_size; (void)ws_size;

  float* ws = (float*)d_ws;
  const size_t BLC = (size_t)NB*NL*NC;           // 1,769,472
  float* u1    = ws;                              // (B,L,192)  layer input / inter-layer
  float* xz    = u1 + BLC;                        // (B,L,1536)
  float* xc    = xz + (size_t)NB*NL*1536;         // (B,L,768)
  float* xdbl  = xc + (size_t)NB*NL*768;          // (B,L,88)
  float* delta = xdbl + (size_t)NB*NL*88;         // (B,L,768), becomes g in-place
  float* ob0 = xc;                                // reuse xc region after scan
  float* ob1 = xc + BLC;

  transpose_in<<<(int)(BLC/256), 256, 0, stream>>>(x, u1);

  for (int layer = 0; layer < 2; ++layer) {
    int pi = layer*2;
    // in_proj, both directions stacked: N=1536, K=192
    sgemm_nt<<<dim3(1536/BN, NM/BM, 1), 256, 0, stream>>>(
        u1, NC, inw + (size_t)pi*768*NC, xz, 1536, 1536, NC, 0, 0, 0);
    // conv + silu
    conv_silu<<<NB*NL*768/256, 256, 0, stream>>>(xz, cw, cb, xc, pi);
    // x_proj: N=44, K=384, z-batched over dir
    sgemm_nt<<<dim3(1, NM/BM, 2), 256, 0, stream>>>(
        xc, 768, xpw + (size_t)pi*XD*DIN, xdbl, 88, XD, DIN, 384, XD*DIN, XD);
    // dt_proj + softplus
    dt_softplus<<<NB*NL*768/256, 256, 0, stream>>>(xdbl, dtw, dtb, delta, pi);
    // selective scan (writes g over delta)
    scan_kernel<<<192, 256, 0, stream>>>(delta, xc, xz, xdbl, alog, dvec, pi);
    // out_proj: N=192, K=384, z-batched over dir
    sgemm_nt<<<dim3(NC/BN, NM/BM, 2), 256, 0, stream>>>(
        delta, 768, outw + (size_t)pi*NC*DIN, ob0, NC, NC, DIN, 384, NC*DIN, (int)BLC);
    if (layer == 0) {
      ln_res<<<NB*NL, NC, 0, stream>>>(ob0, ob1, x, nw, nb, u1);
    } else {
      add_flip<<<(int)(BLC/256), 256, 0, stream>>>(ob0, ob1, outp);
    }
  }
}

// Round 2
// 670.874 us; speedup vs baseline: 2.8331x; 2.8331x over previous
//
#include <hip/hip_runtime.h>
#include <math.h>

#define NB 4
#define NH 48
#define NW 48
#define NC 192
#define NL 2304           // NH*NW
#define NM 9216           // NB*NL
#define DIN 384
#define XD 44             // DT_RANK + 2*D_STATE
#define DTR 12
#define CH 36             // scan chunk length
#define NCHUNK 64         // NL / CH

// ---------------- generic f32 GEMM: C[m,n] = sum_k A[m,k]*Wt[n,k] ----------------
#define BM 128
#define BN 64
#define BK 16
__global__ __launch_bounds__(256) void sgemm_nt(
    const float* __restrict__ A, int lda,
    const float* __restrict__ Wt,
    float* __restrict__ Cm, int ldc,
    int N, int K, int zA, int zW, int zC)
{
  A  += (size_t)blockIdx.z * zA;
  Wt += (size_t)blockIdx.z * zW;
  Cm += (size_t)blockIdx.z * zC;
  __shared__ float As[BK][BM+4];
  __shared__ float Bs[BK][BN+4];
  const int tid = threadIdx.x;
  const int bm = blockIdx.y * BM;
  const int bn = blockIdx.x * BN;
  const int ty = tid >> 4, tx = tid & 15;
  float acc[8][4];
  #pragma unroll
  for (int r = 0; r < 8; ++r)
    #pragma unroll
    for (int c = 0; c < 4; ++c) acc[r][c] = 0.f;

  for (int k0 = 0; k0 < K; k0 += BK) {
    #pragma unroll
    for (int i = 0; i < 2; ++i) {
      int e = tid + i*256;
      int row = e >> 2;
      int k4 = (e & 3) << 2;
      float4 v = *(const float4*)(A + (size_t)(bm+row)*lda + k0 + k4);
      As[k4+0][row]=v.x; As[k4+1][row]=v.y; As[k4+2][row]=v.z; As[k4+3][row]=v.w;
    }
    {
      int n = tid >> 2;
      int k4 = (tid & 3) << 2;
      float4 v = make_float4(0.f,0.f,0.f,0.f);
      if (bn + n < N) v = *(const float4*)(Wt + (size_t)(bn+n)*K + k0 + k4);
      Bs[k4+0][n]=v.x; Bs[k4+1][n]=v.y; Bs[k4+2][n]=v.z; Bs[k4+3][n]=v.w;
    }
    __syncthreads();
    #pragma unroll
    for (int k = 0; k < BK; ++k) {
      float a[8], bb[4];
      #pragma unroll
      for (int r = 0; r < 8; ++r) a[r] = As[k][ty*8+r];
      #pragma unroll
      for (int c = 0; c < 4; ++c) bb[c] = Bs[k][tx*4+c];
      #pragma unroll
      for (int r = 0; r < 8; ++r)
        #pragma unroll
        for (int c = 0; c < 4; ++c) acc[r][c] = fmaf(a[r], bb[c], acc[r][c]);
    }
    __syncthreads();
  }
  #pragma unroll
  for (int r = 0; r < 8; ++r) {
    int m = bm + ty*8 + r;
    #pragma unroll
    for (int c = 0; c < 4; ++c) {
      int n = bn + tx*4 + c;
      if (n < N) Cm[(size_t)m*ldc + n] = acc[r][c];
    }
  }
}

// ---------------- transpose x (B,H,W,C) -> u1 (B, W*H, C) ----------------
__global__ __launch_bounds__(256) void transpose_in(const float* __restrict__ x, float* __restrict__ u1)
{
  int idx = blockIdx.x*256 + threadIdx.x;   // < NB*NL*NC
  int c = idx % NC;
  int rr = idx / NC;
  int s1 = rr % NL;        // w*NH + h
  int b  = rr / NL;
  int hh = s1 % NH;
  int ww = s1 / NH;
  u1[idx] = x[(((size_t)b*NH + hh)*NW + ww)*NC + c];
}

// ---------------- depthwise causal conv (both dirs) + silu ----------------
__global__ __launch_bounds__(256) void conv_silu(
    const float* __restrict__ xz, const float* __restrict__ cw, const float* __restrict__ cb,
    float* __restrict__ xc, int pi)
{
  int idx = blockIdx.x*256 + threadIdx.x;   // < NB*NL*768
  int d2 = idx % 768;
  int r  = idx / 768;      // b*NL + s
  int s  = r % NL;
  int dir = d2 / 384;
  int d = d2 - dir*384;
  int p = pi + dir;
  const float* w = cw + ((size_t)p*DIN + d)*3;
  float acc = cb[p*DIN + d];
  const float* col = xz + (size_t)(r - s)*1536 + (dir*768 + d);
  if (dir == 0) {
    if (s >= 2) acc = fmaf(w[0], col[(size_t)(s-2)*1536], acc);
    if (s >= 1) acc = fmaf(w[1], col[(size_t)(s-1)*1536], acc);
    acc = fmaf(w[2], col[(size_t)s*1536], acc);
  } else {
    if (s+2 < NL) acc = fmaf(w[0], col[(size_t)(s+2)*1536], acc);
    if (s+1 < NL) acc = fmaf(w[1], col[(size_t)(s+1)*1536], acc);
    acc = fmaf(w[2], col[(size_t)s*1536], acc);
  }
  float sg = 1.f / (1.f + __expf(-acc));
  xc[idx] = acc * sg;
}

// ---------------- chunked selective scan ----------------
// pass1: per (b,dir,chunk,d): local scan from h=0; emit P[n]=prod(a), hloc[n].
// ws2 layout: (((bd*NCHUNK + chunk)*32 + slot)*384 + d), slot: n -> P, 16+n -> hloc (then hin).
__global__ __launch_bounds__(384) void scan_pass1(
    const float* __restrict__ xc, const float* __restrict__ xdbl,
    const float* __restrict__ dtw, const float* __restrict__ dtb,
    const float* __restrict__ alog, float* __restrict__ ws2, int pi)
{
  const int chunk = blockIdx.x;
  const int bd = blockIdx.y;       // b*2+dir
  const int b = bd >> 1, dir = bd & 1;
  const int d = threadIdx.x;
  const int p = pi + dir;
  __shared__ float sX[CH][44];
  #pragma unroll
  for (int i = 0; i < 5; ++i) {
    int e = d + i*384;
    if (e < CH*44) {
      int t = e / 44, q = e - t*44;
      int sseq = chunk*CH + t;
      int s = dir ? (NL-1-sseq) : sseq;
      sX[t][q] = xdbl[((size_t)b*NL + s)*88 + dir*XD + q];
    }
  }
  float wdt[DTR];
  #pragma unroll
  for (int k = 0; k < DTR; ++k) wdt[k] = dtw[((size_t)p*DIN + d)*DTR + k];
  const float bdt = dtb[(size_t)p*DIN + d];
  float Ar[16], h[16], P[16];
  #pragma unroll
  for (int n = 0; n < 16; ++n) {
    Ar[n] = -__expf(alog[((size_t)p*DIN + d)*16 + n]);
    h[n] = 0.f; P[n] = 1.f;
  }
  __syncthreads();
  for (int t = 0; t < CH; ++t) {
    int sseq = chunk*CH + t;
    int s = dir ? (NL-1-sseq) : sseq;
    float u = xc[((size_t)b*NL + s)*768 + dir*384 + d];
    float acc = bdt;
    #pragma unroll
    for (int k = 0; k < DTR; ++k) acc = fmaf(sX[t][k], wdt[k], acc);
    float dlt = fmaxf(acc, 0.f) + log1pf(__expf(-fabsf(acc)));
    float du = dlt * u;
    #pragma unroll
    for (int n = 0; n < 16; ++n) {
      float a = __expf(dlt * Ar[n]);
      P[n] *= a;
      h[n] = fmaf(a, h[n], du * sX[t][12+n]);
    }
  }
  size_t base = ((size_t)bd*NCHUNK + chunk)*32*384 + d;
  #pragma unroll
  for (int n = 0; n < 16; ++n) {
    ws2[base + (size_t)n*384] = P[n];
    ws2[base + (size_t)(16+n)*384] = h[n];
  }
}

// prefix over chunks per (bd, n, d); replaces hloc slot with the INCOMING state hin.
__global__ __launch_bounds__(256) void scan_prefix(float* __restrict__ ws2)
{
  int g = blockIdx.x*256 + threadIdx.x;   // < 8*16*384
  int d = g % 384;
  int rest = g / 384;
  int n = rest & 15;
  int bd = rest >> 4;
  float hin = 0.f;
  size_t base = ((size_t)bd*NCHUNK*32 + n)*384 + d;
  for (int j = 0; j < NCHUNK; ++j) {
    size_t ip = base + (size_t)j*32*384;
    float P  = ws2[ip];
    float hl = ws2[ip + (size_t)16*384];
    ws2[ip + (size_t)16*384] = hin;
    hin = fmaf(P, hin, hl);
  }
}

// pass2: rerun chunk from hin; y = C.h + u*D; g = y*silu(z)
__global__ __launch_bounds__(384) void scan_pass2(
    const float* __restrict__ xc, const float* __restrict__ xz,
    const float* __restrict__ xdbl,
    const float* __restrict__ dtw, const float* __restrict__ dtb,
    const float* __restrict__ alog, const float* __restrict__ dvec,
    const float* __restrict__ ws2, float* __restrict__ gout, int pi)
{
  const int chunk = blockIdx.x;
  const int bd = blockIdx.y;
  const int b = bd >> 1, dir = bd & 1;
  const int d = threadIdx.x;
  const int p = pi + dir;
  __shared__ float sX[CH][44];
  #pragma unroll
  for (int i = 0; i < 5; ++i) {
    int e = d + i*384;
    if (e < CH*44) {
      int t = e / 44, q = e - t*44;
      int sseq = chunk*CH + t;
      int s = dir ? (NL-1-sseq) : sseq;
      sX[t][q] = xdbl[((size_t)b*NL + s)*88 + dir*XD + q];
    }
  }
  float wdt[DTR];
  #pragma unroll
  for (int k = 0; k < DTR; ++k) wdt[k] = dtw[((size_t)p*DIN + d)*DTR + k];
  const float bdt = dtb[(size_t)p*DIN + d];
  const float Dreg = dvec[(size_t)p*DIN + d];
  float Ar[16], h[16];
  size_t base = ((size_t)bd*NCHUNK + chunk)*32*384 + d;
  #pragma unroll
  for (int n = 0; n < 16; ++n) {
    Ar[n] = -__expf(alog[((size_t)p*DIN + d)*16 + n]);
    h[n] = ws2[base + (size_t)(16+n)*384];
  }
  __syncthreads();
  for (int t = 0; t < CH; ++t) {
    int sseq = chunk*CH + t;
    int s = dir ? (NL-1-sseq) : sseq;
    size_t row = (size_t)b*NL + s;
    float u = xc[row*768 + dir*384 + d];
    float acc = bdt;
    #pragma unroll
    for (int k = 0; k < DTR; ++k) acc = fmaf(sX[t][k], wdt[k], acc);
    float dlt = fmaxf(acc, 0.f) + log1pf(__expf(-fabsf(acc)));
    float du = dlt * u;
    float y = 0.f;
    #pragma unroll
    for (int n = 0; n < 16; ++n) {
      float a = __expf(dlt * Ar[n]);
      h[n] = fmaf(a, h[n], du * sX[t][12+n]);
      y = fmaf(h[n], sX[t][28+n], y);
    }
    y = fmaf(u, Dreg, y);
    float zv = xz[row*1536 + dir*768 + 384 + d];
    gout[row*768 + dir*384 + d] = y * (zv / (1.f + __expf(-zv)));
  }
}

// ---------------- LayerNorm + residual + transpose back (after layer 1) ----------------
__device__ inline float wave_sum(float v) {
  #pragma unroll
  for (int m = 1; m < 64; m <<= 1) v += __shfl_xor(v, m);
  return v;
}
__global__ __launch_bounds__(192) void ln_res(
    const float* __restrict__ ob0, const float* __restrict__ ob1,
    const float* __restrict__ x, const float* __restrict__ nw, const float* __restrict__ nb2,
    float* __restrict__ u2)
{
  int pb = blockIdx.x;   // b*NL + h*NW + w
  int c = threadIdx.x;
  int b = pb / NL;
  int hw = pb % NL;
  int hh = hw / NW;
  int ww = hw % NW;
  int s1 = ww*NH + hh;
  float v = ob0[((size_t)b*NL + s1)*NC + c] + ob1[((size_t)b*NL + (NL-1-s1))*NC + c];
  __shared__ float red[6];
  float sv = wave_sum(v);
  int wid = c >> 6;
  if ((c & 63) == 0) red[wid] = sv;
  __syncthreads();
  float mean = (red[0]+red[1]+red[2]) * (1.f/NC);
  float dv = v - mean;
  float s2 = wave_sum(dv*dv);
  if ((c & 63) == 0) red[3+wid] = s2;
  __syncthreads();
  float var = (red[3]+red[4]+red[5]) * (1.f/NC);
  u2[(size_t)pb*NC + c] = dv * rsqrtf(var + 1e-5f) * nw[c] + nb2[c] + x[(size_t)pb*NC + c];
}

// ---------------- final add with flip (layer 2 output) ----------------
__global__ __launch_bounds__(256) void add_flip(
    const float* __restrict__ ob0, const float* __restrict__ ob1, float* __restrict__ out)
{
  int idx = blockIdx.x*256 + threadIdx.x;   // < NB*NL*NC
  int c = idx % NC;
  int rr = idx / NC;
  int t = rr % NL;
  int b = rr / NL;
  out[idx] = ob0[idx] + ob1[((size_t)b*NL + (NL-1-t))*NC + c];
}

extern "C" void kernel_launch(void* const* d_in, const int* in_sizes, int n_in,
                              void* d_out, int out_size, void* d_ws, size_t ws_size,
                              hipStream_t stream)
{
  const float* x    = (const float*)d_in[0];
  const float* inw  = (const float*)d_in[1];
  const float* cw   = (const float*)d_in[2];
  const float* cb   = (const float*)d_in[3];
  const float* xpw  = (const float*)d_in[4];
  const float* dtw  = (const float*)d_in[5];
  const float* dtb  = (const float*)d_in[6];
  const float* alog = (const float*)d_in[7];
  const float* dvec = (const float*)d_in[8];
  const float* outw = (const float*)d_in[9];
  const float* nw   = (const float*)d_in[10];
  const float* nb   = (const float*)d_in[11];
  float* outp = (float*)d_out;
  (void)in_sizes; (void)n_in; (void)out_size; (void)ws_size;

  float* ws = (float*)d_ws;
  const size_t BLC = (size_t)NB*NL*NC;            // 1,769,472
  float* u1    = ws;                              // (B,L,192)
  float* xz    = u1 + BLC;                        // (B,L,1536)
  float* xc    = xz + (size_t)NB*NL*1536;         // (B,L,768)
  float* xdbl  = xc + (size_t)NB*NL*768;          // (B,L,88)
  float* gbuf  = xdbl + (size_t)NB*NL*88;         // (B,L,768)
  float* ws2   = gbuf + (size_t)NB*NL*768;        // 8*64*32*384 = 6.29M floats
  float* ob0 = xc;                                // reuse xc region after scan
  float* ob1 = xc + BLC;

  transpose_in<<<(int)(BLC/256), 256, 0, stream>>>(x, u1);

  for (int layer = 0; layer < 2; ++layer) {
    int pi = layer*2;
    // in_proj, both directions stacked: N=1536, K=192
    sgemm_nt<<<dim3(1536/BN, NM/BM, 1), 256, 0, stream>>>(
        u1, NC, inw + (size_t)pi*768*NC, xz, 1536, 1536, NC, 0, 0, 0);
    // conv + silu
    conv_silu<<<NB*NL*768/256, 256, 0, stream>>>(xz, cw, cb, xc, pi);
    // x_proj: N=44, K=384, z-batched over dir
    sgemm_nt<<<dim3(1, NM/BM, 2), 256, 0, stream>>>(
        xc, 768, xpw + (size_t)pi*XD*DIN, xdbl, 88, XD, DIN, 384, XD*DIN, XD);
    // chunked selective scan (fused dt_proj+softplus; writes gbuf)
    scan_pass1<<<dim3(NCHUNK, NB*2), 384, 0, stream>>>(xc, xdbl, dtw, dtb, alog, ws2, pi);
    scan_prefix<<<192, 256, 0, stream>>>(ws2);
    scan_pass2<<<dim3(NCHUNK, NB*2), 384, 0, stream>>>(xc, xz, xdbl, dtw, dtb, alog, dvec, ws2, gbuf, pi);
    // out_proj: N=192, K=384, z-batched over dir
    sgemm_nt<<<dim3(NC/BN, NM/BM, 2), 256, 0, stream>>>(
        gbuf, 768, outw + (size_t)pi*NC*DIN, ob0, NC, NC, DIN, 384, NC*DIN, (int)BLC);
    if (layer == 0) {
      ln_res<<<NB*NL, NC, 0, stream>>>(ob0, ob1, x, nw, nb, u1);
    } else {
      add_flip<<<(int)(BLC/256), 256, 0, stream>>>(ob0, ob1, outp);
    }
  }
}

// Round 3
// 494.538 us; speedup vs baseline: 3.8433x; 1.3566x over previous
//
#include <hip/hip_runtime.h>
#include <math.h>

#define NB 4
#define NH 48
#define NW 48
#define NC 192
#define NL 2304           // NH*NW
#define NM 9216           // NB*NL
#define DIN 384
#define XD 44             // DT_RANK + 2*D_STATE
#define DTR 12
#define CH 36             // scan chunk length
#define NCHUNK 64         // NL / CH

typedef __attribute__((ext_vector_type(8))) short bf16x8;
typedef __attribute__((ext_vector_type(4))) float f32x4;

__device__ inline short f2bf(float f) {
  unsigned u = __builtin_bit_cast(unsigned, f);
  unsigned r = (u + 0x7fffu + ((u >> 16) & 1u)) >> 16;
  return (short)r;
}
__device__ inline float bf2f(short s) {
  unsigned u = ((unsigned)(unsigned short)s) << 16;
  return __builtin_bit_cast(float, u);
}

// ---------------- split-fp32 MFMA GEMM: C[m,n] = sum_k A[m,k]*Wt[n,k] ----------------
// A fp32 (lda), Wt fp32 (N x K row-major), C fp32 (ldc). M multiple of 128.
#define GBM 128
#define GBN 64
#define GBK 32
__global__ __launch_bounds__(256) void mgemm(
    const float* __restrict__ A, int lda,
    const float* __restrict__ Wt,
    float* __restrict__ Cm, int ldc,
    int N, int K, int zA, int zW, int zC)
{
  A  += (size_t)blockIdx.z * zA;
  Wt += (size_t)blockIdx.z * zW;
  Cm += (size_t)blockIdx.z * zC;
  __shared__ short AsH[4][GBM+2][8], AsL[4][GBM+2][8];
  __shared__ short BsH[4][GBN+2][8], BsL[4][GBN+2][8];
  const int tid = threadIdx.x;
  const int l = tid & 63;
  const int wv = tid >> 6;
  const int wr = wv >> 1, wc = wv & 1;
  const int bm = blockIdx.y * GBM;
  const int bn = blockIdx.x * GBN;
  const int lrow = l & 15;
  const int lkb = l >> 4;

  f32x4 acc[4][2];
  #pragma unroll
  for (int mi = 0; mi < 4; ++mi)
    #pragma unroll
    for (int ni = 0; ni < 2; ++ni) acc[mi][ni] = (f32x4)0.f;

  for (int k0 = 0; k0 < K; k0 += GBK) {
    // stage A tile 128x32: 512 octets, 2 per thread
    #pragma unroll
    for (int i = 0; i < 2; ++i) {
      int o = tid + i*256;
      int row = o >> 2, kb = o & 3;
      const float* src = A + (size_t)(bm + row)*lda + k0 + kb*8;
      float4 v0 = *(const float4*)src;
      float4 v1 = *(const float4*)(src + 4);
      float vv[8] = {v0.x,v0.y,v0.z,v0.w,v1.x,v1.y,v1.z,v1.w};
      bf16x8 hi, lo;
      #pragma unroll
      for (int j = 0; j < 8; ++j) {
        short h = f2bf(vv[j]);
        hi[j] = h;
        lo[j] = f2bf(vv[j] - bf2f(h));
      }
      *(bf16x8*)&AsH[kb][row][0] = hi;
      *(bf16x8*)&AsL[kb][row][0] = lo;
    }
    // stage B tile 64x32: 256 octets, 1 per thread
    {
      int n = tid >> 2, kb = tid & 3;
      float4 v0 = make_float4(0.f,0.f,0.f,0.f), v1 = v0;
      if (bn + n < N) {
        const float* src = Wt + (size_t)(bn + n)*K + k0 + kb*8;
        v0 = *(const float4*)src;
        v1 = *(const float4*)(src + 4);
      }
      float vv[8] = {v0.x,v0.y,v0.z,v0.w,v1.x,v1.y,v1.z,v1.w};
      bf16x8 hi, lo;
      #pragma unroll
      for (int j = 0; j < 8; ++j) {
        short h = f2bf(vv[j]);
        hi[j] = h;
        lo[j] = f2bf(vv[j] - bf2f(h));
      }
      *(bf16x8*)&BsH[kb][n][0] = hi;
      *(bf16x8*)&BsL[kb][n][0] = lo;
    }
    __syncthreads();
    bf16x8 ah[4], al[4], bh[2], bl[2];
    #pragma unroll
    for (int mi = 0; mi < 4; ++mi) {
      int row = wr*64 + mi*16 + lrow;
      ah[mi] = *(const bf16x8*)&AsH[lkb][row][0];
      al[mi] = *(const bf16x8*)&AsL[lkb][row][0];
    }
    #pragma unroll
    for (int ni = 0; ni < 2; ++ni) {
      int rn = wc*32 + ni*16 + lrow;
      bh[ni] = *(const bf16x8*)&BsH[lkb][rn][0];
      bl[ni] = *(const bf16x8*)&BsL[lkb][rn][0];
    }
    #pragma unroll
    for (int mi = 0; mi < 4; ++mi)
      #pragma unroll
      for (int ni = 0; ni < 2; ++ni) {
        acc[mi][ni] = __builtin_amdgcn_mfma_f32_16x16x32_bf16(ah[mi], bh[ni], acc[mi][ni], 0, 0, 0);
        acc[mi][ni] = __builtin_amdgcn_mfma_f32_16x16x32_bf16(ah[mi], bl[ni], acc[mi][ni], 0, 0, 0);
        acc[mi][ni] = __builtin_amdgcn_mfma_f32_16x16x32_bf16(al[mi], bh[ni], acc[mi][ni], 0, 0, 0);
      }
    __syncthreads();
  }
  // store: C/D layout col=lane&15, row=(lane>>4)*4+reg
  #pragma unroll
  for (int mi = 0; mi < 4; ++mi)
    #pragma unroll
    for (int ni = 0; ni < 2; ++ni) {
      int n = bn + wc*32 + ni*16 + lrow;
      if (n < N) {
        #pragma unroll
        for (int r = 0; r < 4; ++r) {
          int m = bm + wr*64 + mi*16 + lkb*4 + r;
          Cm[(size_t)m*ldc + n] = acc[mi][ni][r];
        }
      }
    }
}

// ---------------- transpose x (B,H,W,C) -> u1 (B, W*H, C) ----------------
__global__ __launch_bounds__(256) void transpose_in(const float* __restrict__ x, float* __restrict__ u1)
{
  int idx = blockIdx.x*256 + threadIdx.x;   // < NB*NL*NC
  int c = idx % NC;
  int rr = idx / NC;
  int s1 = rr % NL;        // w*NH + h
  int b  = rr / NL;
  int hh = s1 % NH;
  int ww = s1 / NH;
  u1[idx] = x[(((size_t)b*NH + hh)*NW + ww)*NC + c];
}

// ---------------- depthwise causal conv (both dirs) + silu ----------------
__global__ __launch_bounds__(256) void conv_silu(
    const float* __restrict__ xz, const float* __restrict__ cw, const float* __restrict__ cb,
    float* __restrict__ xc, int pi)
{
  int idx = blockIdx.x*256 + threadIdx.x;   // < NB*NL*768
  int d2 = idx % 768;
  int r  = idx / 768;      // b*NL + s
  int s  = r % NL;
  int dir = d2 / 384;
  int d = d2 - dir*384;
  int p = pi + dir;
  const float* w = cw + ((size_t)p*DIN + d)*3;
  float acc = cb[p*DIN + d];
  const float* col = xz + (size_t)(r - s)*1536 + (dir*768 + d);
  if (dir == 0) {
    if (s >= 2) acc = fmaf(w[0], col[(size_t)(s-2)*1536], acc);
    if (s >= 1) acc = fmaf(w[1], col[(size_t)(s-1)*1536], acc);
    acc = fmaf(w[2], col[(size_t)s*1536], acc);
  } else {
    if (s+2 < NL) acc = fmaf(w[0], col[(size_t)(s+2)*1536], acc);
    if (s+1 < NL) acc = fmaf(w[1], col[(size_t)(s+1)*1536], acc);
    acc = fmaf(w[2], col[(size_t)s*1536], acc);
  }
  float sg = 1.f / (1.f + __expf(-acc));
  xc[idx] = acc * sg;
}

// ---------------- chunked selective scan ----------------
__global__ __launch_bounds__(384) void scan_pass1(
    const float* __restrict__ xc, const float* __restrict__ xdbl,
    const float* __restrict__ dtw, const float* __restrict__ dtb,
    const float* __restrict__ alog, float* __restrict__ ws2, int pi)
{
  const int chunk = blockIdx.x;
  const int bd = blockIdx.y;       // b*2+dir
  const int b = bd >> 1, dir = bd & 1;
  const int d = threadIdx.x;
  const int p = pi + dir;
  __shared__ float sX[CH][44];
  #pragma unroll
  for (int i = 0; i < 5; ++i) {
    int e = d + i*384;
    if (e < CH*44) {
      int t = e / 44, q = e - t*44;
      int sseq = chunk*CH + t;
      int s = dir ? (NL-1-sseq) : sseq;
      sX[t][q] = xdbl[((size_t)b*NL + s)*88 + dir*XD + q];
    }
  }
  float wdt[DTR];
  #pragma unroll
  for (int k = 0; k < DTR; ++k) wdt[k] = dtw[((size_t)p*DIN + d)*DTR + k];
  const float bdt = dtb[(size_t)p*DIN + d];
  float Ar[16], h[16], P[16];
  #pragma unroll
  for (int n = 0; n < 16; ++n) {
    Ar[n] = -__expf(alog[((size_t)p*DIN + d)*16 + n]);
    h[n] = 0.f; P[n] = 1.f;
  }
  __syncthreads();
  for (int t = 0; t < CH; ++t) {
    int sseq = chunk*CH + t;
    int s = dir ? (NL-1-sseq) : sseq;
    float u = xc[((size_t)b*NL + s)*768 + dir*384 + d];
    float acc = bdt;
    #pragma unroll
    for (int k = 0; k < DTR; ++k) acc = fmaf(sX[t][k], wdt[k], acc);
    float dlt = fmaxf(acc, 0.f) + log1pf(__expf(-fabsf(acc)));
    float du = dlt * u;
    #pragma unroll
    for (int n = 0; n < 16; ++n) {
      float a = __expf(dlt * Ar[n]);
      P[n] *= a;
      h[n] = fmaf(a, h[n], du * sX[t][12+n]);
    }
  }
  size_t base = ((size_t)bd*NCHUNK + chunk)*32*384 + d;
  #pragma unroll
  for (int n = 0; n < 16; ++n) {
    ws2[base + (size_t)n*384] = P[n];
    ws2[base + (size_t)(16+n)*384] = h[n];
  }
}

__global__ __launch_bounds__(256) void scan_prefix(float* __restrict__ ws2)
{
  int g = blockIdx.x*256 + threadIdx.x;   // < 8*16*384
  int d = g % 384;
  int rest = g / 384;
  int n = rest & 15;
  int bd = rest >> 4;
  float hin = 0.f;
  size_t base = ((size_t)bd*NCHUNK*32 + n)*384 + d;
  for (int j = 0; j < NCHUNK; ++j) {
    size_t ip = base + (size_t)j*32*384;
    float P  = ws2[ip];
    float hl = ws2[ip + (size_t)16*384];
    ws2[ip + (size_t)16*384] = hin;
    hin = fmaf(P, hin, hl);
  }
}

__global__ __launch_bounds__(384) void scan_pass2(
    const float* __restrict__ xc, const float* __restrict__ xz,
    const float* __restrict__ xdbl,
    const float* __restrict__ dtw, const float* __restrict__ dtb,
    const float* __restrict__ alog, const float* __restrict__ dvec,
    const float* __restrict__ ws2, float* __restrict__ gout, int pi)
{
  const int chunk = blockIdx.x;
  const int bd = blockIdx.y;
  const int b = bd >> 1, dir = bd & 1;
  const int d = threadIdx.x;
  const int p = pi + dir;
  __shared__ float sX[CH][44];
  #pragma unroll
  for (int i = 0; i < 5; ++i) {
    int e = d + i*384;
    if (e < CH*44) {
      int t = e / 44, q = e - t*44;
      int sseq = chunk*CH + t;
      int s = dir ? (NL-1-sseq) : sseq;
      sX[t][q] = xdbl[((size_t)b*NL + s)*88 + dir*XD + q];
    }
  }
  float wdt[DTR];
  #pragma unroll
  for (int k = 0; k < DTR; ++k) wdt[k] = dtw[((size_t)p*DIN + d)*DTR + k];
  const float bdt = dtb[(size_t)p*DIN + d];
  const float Dreg = dvec[(size_t)p*DIN + d];
  float Ar[16], h[16];
  size_t base = ((size_t)bd*NCHUNK + chunk)*32*384 + d;
  #pragma unroll
  for (int n = 0; n < 16; ++n) {
    Ar[n] = -__expf(alog[((size_t)p*DIN + d)*16 + n]);
    h[n] = ws2[base + (size_t)(16+n)*384];
  }
  __syncthreads();
  for (int t = 0; t < CH; ++t) {
    int sseq = chunk*CH + t;
    int s = dir ? (NL-1-sseq) : sseq;
    size_t row = (size_t)b*NL + s;
    float u = xc[row*768 + dir*384 + d];
    float acc = bdt;
    #pragma unroll
    for (int k = 0; k < DTR; ++k) acc = fmaf(sX[t][k], wdt[k], acc);
    float dlt = fmaxf(acc, 0.f) + log1pf(__expf(-fabsf(acc)));
    float du = dlt * u;
    float y = 0.f;
    #pragma unroll
    for (int n = 0; n < 16; ++n) {
      float a = __expf(dlt * Ar[n]);
      h[n] = fmaf(a, h[n], du * sX[t][12+n]);
      y = fmaf(h[n], sX[t][28+n], y);
    }
    y = fmaf(u, Dreg, y);
    float zv = xz[row*1536 + dir*768 + 384 + d];
    gout[row*768 + dir*384 + d] = y * (zv / (1.f + __expf(-zv)));
  }
}

// ---------------- LayerNorm + residual + transpose back (after layer 1) ----------------
__device__ inline float wave_sum(float v) {
  #pragma unroll
  for (int m = 1; m < 64; m <<= 1) v += __shfl_xor(v, m);
  return v;
}
__global__ __launch_bounds__(192) void ln_res(
    const float* __restrict__ ob0, const float* __restrict__ ob1,
    const float* __restrict__ x, const float* __restrict__ nw, const float* __restrict__ nb2,
    float* __restrict__ u2)
{
  int pb = blockIdx.x;   // b*NL + h*NW + w
  int c = threadIdx.x;
  int b = pb / NL;
  int hw = pb % NL;
  int hh = hw / NW;
  int ww = hw % NW;
  int s1 = ww*NH + hh;
  float v = ob0[((size_t)b*NL + s1)*NC + c] + ob1[((size_t)b*NL + (NL-1-s1))*NC + c];
  __shared__ float red[6];
  float sv = wave_sum(v);
  int wid = c >> 6;
  if ((c & 63) == 0) red[wid] = sv;
  __syncthreads();
  float mean = (red[0]+red[1]+red[2]) * (1.f/NC);
  float dv = v - mean;
  float s2 = wave_sum(dv*dv);
  if ((c & 63) == 0) red[3+wid] = s2;
  __syncthreads();
  float var = (red[3]+red[4]+red[5]) * (1.f/NC);
  u2[(size_t)pb*NC + c] = dv * rsqrtf(var + 1e-5f) * nw[c] + nb2[c] + x[(size_t)pb*NC + c];
}

// ---------------- final add with flip (layer 2 output) ----------------
__global__ __launch_bounds__(256) void add_flip(
    const float* __restrict__ ob0, const float* __restrict__ ob1, float* __restrict__ out)
{
  int idx = blockIdx.x*256 + threadIdx.x;   // < NB*NL*NC
  int c = idx % NC;
  int rr = idx / NC;
  int t = rr % NL;
  int b = rr / NL;
  out[idx] = ob0[idx] + ob1[((size_t)b*NL + (NL-1-t))*NC + c];
}

extern "C" void kernel_launch(void* const* d_in, const int* in_sizes, int n_in,
                              void* d_out, int out_size, void* d_ws, size_t ws_size,
                              hipStream_t stream)
{
  const float* x    = (const float*)d_in[0];
  const float* inw  = (const float*)d_in[1];
  const float* cw   = (const float*)d_in[2];
  const float* cb   = (const float*)d_in[3];
  const float* xpw  = (const float*)d_in[4];
  const float* dtw  = (const float*)d_in[5];
  const float* dtb  = (const float*)d_in[6];
  const float* alog = (const float*)d_in[7];
  const float* dvec = (const float*)d_in[8];
  const float* outw = (const float*)d_in[9];
  const float* nw   = (const float*)d_in[10];
  const float* nb   = (const float*)d_in[11];
  float* outp = (float*)d_out;
  (void)in_sizes; (void)n_in; (void)out_size; (void)ws_size;

  float* ws = (float*)d_ws;
  const size_t BLC = (size_t)NB*NL*NC;            // 1,769,472
  float* u1    = ws;                              // (B,L,192)
  float* xz    = u1 + BLC;                        // (B,L,1536)
  float* xc    = xz + (size_t)NB*NL*1536;         // (B,L,768)
  float* xdbl  = xc + (size_t)NB*NL*768;          // (B,L,88)
  float* gbuf  = xdbl + (size_t)NB*NL*88;         // (B,L,768)
  float* ws2   = gbuf + (size_t)NB*NL*768;        // 8*64*32*384 floats
  float* ob0 = xc;                                // reuse xc region after scan
  float* ob1 = xc + BLC;

  transpose_in<<<(int)(BLC/256), 256, 0, stream>>>(x, u1);

  for (int layer = 0; layer < 2; ++layer) {
    int pi = layer*2;
    // in_proj, both directions stacked: N=1536, K=192
    mgemm<<<dim3(1536/GBN, NM/GBM, 1), 256, 0, stream>>>(
        u1, NC, inw + (size_t)pi*768*NC, xz, 1536, 1536, NC, 0, 0, 0);
    // conv + silu
    conv_silu<<<NB*NL*768/256, 256, 0, stream>>>(xz, cw, cb, xc, pi);
    // x_proj: N=44, K=384, z-batched over dir
    mgemm<<<dim3(1, NM/GBM, 2), 256, 0, stream>>>(
        xc, 768, xpw + (size_t)pi*XD*DIN, xdbl, 88, XD, DIN, 384, XD*DIN, XD);
    // chunked selective scan (fused dt_proj+softplus; writes gbuf)
    scan_pass1<<<dim3(NCHUNK, NB*2), 384, 0, stream>>>(xc, xdbl, dtw, dtb, alog, ws2, pi);
    scan_prefix<<<192, 256, 0, stream>>>(ws2);
    scan_pass2<<<dim3(NCHUNK, NB*2), 384, 0, stream>>>(xc, xz, xdbl, dtw, dtb, alog, dvec, ws2, gbuf, pi);
    // out_proj: N=192, K=384, z-batched over dir
    mgemm<<<dim3(NC/GBN, NM/GBM, 2), 256, 0, stream>>>(
        gbuf, 768, outw + (size_t)pi*NC*DIN, ob0, NC, NC, DIN, 384, NC*DIN, (int)BLC);
    if (layer == 0) {
      ln_res<<<NB*NL, NC, 0, stream>>>(ob0, ob1, x, nw, nb, u1);
    } else {
      add_flip<<<(int)(BLC/256), 256, 0, stream>>>(ob0, ob1, outp);
    }
  }
}

// Round 4
// 372.232 us; speedup vs baseline: 5.1060x; 1.3286x over previous
//
#include <hip/hip_runtime.h>
#include <math.h>

#define NB 4
#define NH 48
#define NW 48
#define NC 192
#define NL 2304           // NH*NW
#define NM 9216           // NB*NL
#define DIN 384
#define XD 44             // DT_RANK + 2*D_STATE
#define DTR 12
#define CH 24             // scan chunk length
#define NCHUNK 96         // NL / CH

typedef __attribute__((ext_vector_type(8))) short bf16x8;
typedef __attribute__((ext_vector_type(4))) float f32x4;

__device__ inline short f2bf(float f) {
  unsigned u = __builtin_bit_cast(unsigned, f);
  unsigned r = (u + 0x7fffu + ((u >> 16) & 1u)) >> 16;
  return (short)r;
}
__device__ inline float bf2f(short s) {
  unsigned u = ((unsigned)(unsigned short)s) << 16;
  return __builtin_bit_cast(float, u);
}
__device__ inline float fexp2(float x) { return __builtin_amdgcn_exp2f(x); }
__device__ inline float flog2(float x) { return __builtin_amdgcn_logf(x); }
#define LOG2E 1.4426950408889634f
#define LN2   0.6931471805599453f

// ---------------- split-fp32 MFMA GEMM: C[m,n] = sum_k A[m,k]*Wt[n,k] ----------------
#define GBM 128
#define GBN 64
#define GBK 32
__global__ __launch_bounds__(256) void mgemm(
    const float* __restrict__ A, int lda,
    const float* __restrict__ Wt,
    float* __restrict__ Cm, int ldc,
    int N, int K, int zA, int zW, int zC)
{
  A  += (size_t)blockIdx.z * zA;
  Wt += (size_t)blockIdx.z * zW;
  Cm += (size_t)blockIdx.z * zC;
  __shared__ short AsH[4][GBM+2][8], AsL[4][GBM+2][8];
  __shared__ short BsH[4][GBN+2][8], BsL[4][GBN+2][8];
  const int tid = threadIdx.x;
  const int l = tid & 63;
  const int wv = tid >> 6;
  const int wr = wv >> 1, wc = wv & 1;
  const int bm = blockIdx.y * GBM;
  const int bn = blockIdx.x * GBN;
  const int lrow = l & 15;
  const int lkb = l >> 4;

  f32x4 acc[4][2];
  #pragma unroll
  for (int mi = 0; mi < 4; ++mi)
    #pragma unroll
    for (int ni = 0; ni < 2; ++ni) acc[mi][ni] = (f32x4)0.f;

  for (int k0 = 0; k0 < K; k0 += GBK) {
    #pragma unroll
    for (int i = 0; i < 2; ++i) {
      int o = tid + i*256;
      int row = o >> 2, kb = o & 3;
      const float* src = A + (size_t)(bm + row)*lda + k0 + kb*8;
      float4 v0 = *(const float4*)src;
      float4 v1 = *(const float4*)(src + 4);
      float vv[8] = {v0.x,v0.y,v0.z,v0.w,v1.x,v1.y,v1.z,v1.w};
      bf16x8 hi, lo;
      #pragma unroll
      for (int j = 0; j < 8; ++j) {
        short h = f2bf(vv[j]);
        hi[j] = h;
        lo[j] = f2bf(vv[j] - bf2f(h));
      }
      *(bf16x8*)&AsH[kb][row][0] = hi;
      *(bf16x8*)&AsL[kb][row][0] = lo;
    }
    {
      int n = tid >> 2, kb = tid & 3;
      float4 v0 = make_float4(0.f,0.f,0.f,0.f), v1 = v0;
      if (bn + n < N) {
        const float* src = Wt + (size_t)(bn + n)*K + k0 + kb*8;
        v0 = *(const float4*)src;
        v1 = *(const float4*)(src + 4);
      }
      float vv[8] = {v0.x,v0.y,v0.z,v0.w,v1.x,v1.y,v1.z,v1.w};
      bf16x8 hi, lo;
      #pragma unroll
      for (int j = 0; j < 8; ++j) {
        short h = f2bf(vv[j]);
        hi[j] = h;
        lo[j] = f2bf(vv[j] - bf2f(h));
      }
      *(bf16x8*)&BsH[kb][n][0] = hi;
      *(bf16x8*)&BsL[kb][n][0] = lo;
    }
    __syncthreads();
    bf16x8 ah[4], al[4], bh[2], bl[2];
    #pragma unroll
    for (int mi = 0; mi < 4; ++mi) {
      int row = wr*64 + mi*16 + lrow;
      ah[mi] = *(const bf16x8*)&AsH[lkb][row][0];
      al[mi] = *(const bf16x8*)&AsL[lkb][row][0];
    }
    #pragma unroll
    for (int ni = 0; ni < 2; ++ni) {
      int rn = wc*32 + ni*16 + lrow;
      bh[ni] = *(const bf16x8*)&BsH[lkb][rn][0];
      bl[ni] = *(const bf16x8*)&BsL[lkb][rn][0];
    }
    #pragma unroll
    for (int mi = 0; mi < 4; ++mi)
      #pragma unroll
      for (int ni = 0; ni < 2; ++ni) {
        acc[mi][ni] = __builtin_amdgcn_mfma_f32_16x16x32_bf16(ah[mi], bh[ni], acc[mi][ni], 0, 0, 0);
        acc[mi][ni] = __builtin_amdgcn_mfma_f32_16x16x32_bf16(ah[mi], bl[ni], acc[mi][ni], 0, 0, 0);
        acc[mi][ni] = __builtin_amdgcn_mfma_f32_16x16x32_bf16(al[mi], bh[ni], acc[mi][ni], 0, 0, 0);
      }
    __syncthreads();
  }
  #pragma unroll
  for (int mi = 0; mi < 4; ++mi)
    #pragma unroll
    for (int ni = 0; ni < 2; ++ni) {
      int n = bn + wc*32 + ni*16 + lrow;
      if (n < N) {
        #pragma unroll
        for (int r = 0; r < 4; ++r) {
          int m = bm + wr*64 + mi*16 + lkb*4 + r;
          Cm[(size_t)m*ldc + n] = acc[mi][ni][r];
        }
      }
    }
}

// ---------------- transpose x (B,H,W,C) -> u1 (B, W*H, C) ----------------
__global__ __launch_bounds__(256) void transpose_in(const float* __restrict__ x, float* __restrict__ u1)
{
  int idx = blockIdx.x*256 + threadIdx.x;
  int c = idx % NC;
  int rr = idx / NC;
  int s1 = rr % NL;
  int b  = rr / NL;
  int hh = s1 % NH;
  int ww = s1 / NH;
  u1[idx] = x[(((size_t)b*NH + hh)*NW + ww)*NC + c];
}

// ---------------- depthwise causal conv (both dirs) + silu ----------------
__global__ __launch_bounds__(256) void conv_silu(
    const float* __restrict__ xz, const float* __restrict__ cw, const float* __restrict__ cb,
    float* __restrict__ xc, int pi)
{
  int idx = blockIdx.x*256 + threadIdx.x;
  int d2 = idx % 768;
  int r  = idx / 768;
  int s  = r % NL;
  int dir = d2 / 384;
  int d = d2 - dir*384;
  int p = pi + dir;
  const float* w = cw + ((size_t)p*DIN + d)*3;
  float acc = cb[p*DIN + d];
  const float* col = xz + (size_t)(r - s)*1536 + (dir*768 + d);
  if (dir == 0) {
    if (s >= 2) acc = fmaf(w[0], col[(size_t)(s-2)*1536], acc);
    if (s >= 1) acc = fmaf(w[1], col[(size_t)(s-1)*1536], acc);
    acc = fmaf(w[2], col[(size_t)s*1536], acc);
  } else {
    if (s+2 < NL) acc = fmaf(w[0], col[(size_t)(s+2)*1536], acc);
    if (s+1 < NL) acc = fmaf(w[1], col[(size_t)(s+1)*1536], acc);
    acc = fmaf(w[2], col[(size_t)s*1536], acc);
  }
  float sg = 1.f / (1.f + fexp2(-acc*LOG2E));
  xc[idx] = acc * sg;
}

// ---------------- chunked selective scan ----------------
// pass1: local scan; writes delta -> dlt (=gbuf), P & hloc -> ws2.
__global__ __launch_bounds__(384) void scan_pass1(
    const float* __restrict__ xc, const float* __restrict__ xdbl,
    const float* __restrict__ dtw, const float* __restrict__ dtb,
    const float* __restrict__ alog, float* __restrict__ ws2,
    float* __restrict__ dlt_out, int pi)
{
  const int chunk = blockIdx.x;
  const int bd = blockIdx.y;
  const int b = bd >> 1, dir = bd & 1;
  const int d = threadIdx.x;
  const int p = pi + dir;
  __shared__ float sX[CH][28];   // 0..11 dt, 12..27 B
  for (int e = d; e < CH*28; e += 384) {
    int t = e / 28, q = e - t*28;
    int sseq = chunk*CH + t;
    int s = dir ? (NL-1-sseq) : sseq;
    sX[t][q] = xdbl[((size_t)b*NL + s)*88 + dir*XD + q];
  }
  float wdt[DTR];
  #pragma unroll
  for (int k = 0; k < DTR; ++k) wdt[k] = dtw[((size_t)p*DIN + d)*DTR + k];
  const float bdt = dtb[(size_t)p*DIN + d];
  float Ar2[16], h[16];
  #pragma unroll
  for (int n = 0; n < 16; ++n) {
    Ar2[n] = -__expf(alog[((size_t)p*DIN + d)*16 + n]) * LOG2E;
    h[n] = 0.f;
  }
  float cum = 0.f;
  __syncthreads();
  #pragma unroll 2
  for (int t = 0; t < CH; ++t) {
    int sseq = chunk*CH + t;
    int s = dir ? (NL-1-sseq) : sseq;
    size_t row = (size_t)b*NL + s;
    float u = xc[row*768 + dir*384 + d];
    float acc = bdt;
    #pragma unroll
    for (int k = 0; k < DTR; ++k) acc = fmaf(sX[t][k], wdt[k], acc);
    float e1 = fexp2(-fabsf(acc)*LOG2E);
    float dlt = fmaxf(acc, 0.f) + LN2*flog2(1.f + e1);
    cum += dlt;
    dlt_out[row*768 + dir*384 + d] = dlt;
    float du = dlt * u;
    #pragma unroll
    for (int n = 0; n < 16; ++n) {
      float a = fexp2(dlt * Ar2[n]);
      h[n] = fmaf(a, h[n], du * sX[t][12+n]);
    }
  }
  size_t base = ((size_t)bd*NCHUNK + chunk)*32*384 + d;
  #pragma unroll
  for (int n = 0; n < 16; ++n) {
    ws2[base + (size_t)n*384] = fexp2(cum * Ar2[n]);
    ws2[base + (size_t)(16+n)*384] = h[n];
  }
}

// prefix over chunks per (bd, n, d); replaces hloc slot with incoming state hin.
__global__ __launch_bounds__(256) void scan_prefix(float* __restrict__ ws2)
{
  int g = blockIdx.x*256 + threadIdx.x;   // < 8*16*384
  int d = g % 384;
  int rest = g / 384;
  int n = rest & 15;
  int bd = rest >> 4;
  float hin = 0.f;
  size_t base = ((size_t)bd*NCHUNK*32 + n)*384 + d;
  for (int j = 0; j < NCHUNK; j += 8) {
    float Pv[8], hv[8];
    #pragma unroll
    for (int u = 0; u < 8; ++u) {
      size_t ip = base + (size_t)(j+u)*32*384;
      Pv[u] = ws2[ip];
      hv[u] = ws2[ip + (size_t)16*384];
    }
    #pragma unroll
    for (int u = 0; u < 8; ++u) {
      size_t ip = base + (size_t)(j+u)*32*384;
      ws2[ip + (size_t)16*384] = hin;
      hin = fmaf(Pv[u], hin, hv[u]);
    }
  }
}

// pass2: rerun chunk from hin using stored delta; writes g over delta in place.
__global__ __launch_bounds__(384) void scan_pass2(
    const float* __restrict__ xc, const float* __restrict__ xz,
    const float* __restrict__ xdbl, const float* __restrict__ alog,
    const float* __restrict__ dvec, const float* __restrict__ ws2,
    float* __restrict__ gio, int pi)
{
  const int chunk = blockIdx.x;
  const int bd = blockIdx.y;
  const int b = bd >> 1, dir = bd & 1;
  const int d = threadIdx.x;
  const int p = pi + dir;
  __shared__ float sX[CH][32];   // 0..15 B, 16..31 C
  for (int e = d; e < CH*32; e += 384) {
    int t = e / 32, q = e - t*32;
    int sseq = chunk*CH + t;
    int s = dir ? (NL-1-sseq) : sseq;
    sX[t][q] = xdbl[((size_t)b*NL + s)*88 + dir*XD + 12 + q];
  }
  const float Dreg = dvec[(size_t)p*DIN + d];
  float Ar2[16], h[16];
  size_t base = ((size_t)bd*NCHUNK + chunk)*32*384 + d;
  #pragma unroll
  for (int n = 0; n < 16; ++n) {
    Ar2[n] = -__expf(alog[((size_t)p*DIN + d)*16 + n]) * LOG2E;
    h[n] = ws2[base + (size_t)(16+n)*384];
  }
  __syncthreads();
  #pragma unroll 2
  for (int t = 0; t < CH; ++t) {
    int sseq = chunk*CH + t;
    int s = dir ? (NL-1-sseq) : sseq;
    size_t row = (size_t)b*NL + s;
    size_t gidx = row*768 + dir*384 + d;
    float dlt = gio[gidx];
    float u = xc[gidx];
    float zv = xz[row*1536 + dir*768 + 384 + d];
    float du = dlt * u;
    float y = 0.f;
    #pragma unroll
    for (int n = 0; n < 16; ++n) {
      float a = fexp2(dlt * Ar2[n]);
      h[n] = fmaf(a, h[n], du * sX[t][n]);
      y = fmaf(h[n], sX[t][16+n], y);
    }
    y = fmaf(u, Dreg, y);
    float sg = 1.f / (1.f + fexp2(-zv*LOG2E));
    gio[gidx] = y * (zv * sg);
  }
}

// ---------------- LayerNorm + residual + transpose back (after layer 1) ----------------
__device__ inline float wave_sum(float v) {
  #pragma unroll
  for (int m = 1; m < 64; m <<= 1) v += __shfl_xor(v, m);
  return v;
}
__global__ __launch_bounds__(192) void ln_res(
    const float* __restrict__ ob0, const float* __restrict__ ob1,
    const float* __restrict__ x, const float* __restrict__ nw, const float* __restrict__ nb2,
    float* __restrict__ u2)
{
  int pb = blockIdx.x;
  int c = threadIdx.x;
  int b = pb / NL;
  int hw = pb % NL;
  int hh = hw / NW;
  int ww = hw % NW;
  int s1 = ww*NH + hh;
  float v = ob0[((size_t)b*NL + s1)*NC + c] + ob1[((size_t)b*NL + (NL-1-s1))*NC + c];
  __shared__ float red[6];
  float sv = wave_sum(v);
  int wid = c >> 6;
  if ((c & 63) == 0) red[wid] = sv;
  __syncthreads();
  float mean = (red[0]+red[1]+red[2]) * (1.f/NC);
  float dv = v - mean;
  float s2 = wave_sum(dv*dv);
  if ((c & 63) == 0) red[3+wid] = s2;
  __syncthreads();
  float var = (red[3]+red[4]+red[5]) * (1.f/NC);
  u2[(size_t)pb*NC + c] = dv * rsqrtf(var + 1e-5f) * nw[c] + nb2[c] + x[(size_t)pb*NC + c];
}

// ---------------- final add with flip (layer 2 output) ----------------
__global__ __launch_bounds__(256) void add_flip(
    const float* __restrict__ ob0, const float* __restrict__ ob1, float* __restrict__ out)
{
  int idx = blockIdx.x*256 + threadIdx.x;
  int c = idx % NC;
  int rr = idx / NC;
  int t = rr % NL;
  int b = rr / NL;
  out[idx] = ob0[idx] + ob1[((size_t)b*NL + (NL-1-t))*NC + c];
}

extern "C" void kernel_launch(void* const* d_in, const int* in_sizes, int n_in,
                              void* d_out, int out_size, void* d_ws, size_t ws_size,
                              hipStream_t stream)
{
  const float* x    = (const float*)d_in[0];
  const float* inw  = (const float*)d_in[1];
  const float* cw   = (const float*)d_in[2];
  const float* cb   = (const float*)d_in[3];
  const float* xpw  = (const float*)d_in[4];
  const float* dtw  = (const float*)d_in[5];
  const float* dtb  = (const float*)d_in[6];
  const float* alog = (const float*)d_in[7];
  const float* dvec = (const float*)d_in[8];
  const float* outw = (const float*)d_in[9];
  const float* nw   = (const float*)d_in[10];
  const float* nb   = (const float*)d_in[11];
  float* outp = (float*)d_out;
  (void)in_sizes; (void)n_in; (void)out_size; (void)ws_size;

  float* ws = (float*)d_ws;
  const size_t BLC = (size_t)NB*NL*NC;            // 1,769,472
  float* u1    = ws;                              // (B,L,192)
  float* xz    = u1 + BLC;                        // (B,L,1536)
  float* xc    = xz + (size_t)NB*NL*1536;         // (B,L,768)
  float* xdbl  = xc + (size_t)NB*NL*768;          // (B,L,88)
  float* gbuf  = xdbl + (size_t)NB*NL*88;         // (B,L,768): delta then g, in place
  float* ws2   = gbuf + (size_t)NB*NL*768;        // 8*NCHUNK*32*384 floats
  float* ob0 = xc;                                // reuse xc region after out_proj
  float* ob1 = xc + BLC;

  transpose_in<<<(int)(BLC/256), 256, 0, stream>>>(x, u1);

  for (int layer = 0; layer < 2; ++layer) {
    int pi = layer*2;
    // in_proj, both directions stacked: N=1536, K=192
    mgemm<<<dim3(1536/GBN, NM/GBM, 1), 256, 0, stream>>>(
        u1, NC, inw + (size_t)pi*768*NC, xz, 1536, 1536, NC, 0, 0, 0);
    // conv + silu
    conv_silu<<<NB*NL*768/256, 256, 0, stream>>>(xz, cw, cb, xc, pi);
    // x_proj: N=44, K=384, z-batched over dir
    mgemm<<<dim3(1, NM/GBM, 2), 256, 0, stream>>>(
        xc, 768, xpw + (size_t)pi*XD*DIN, xdbl, 88, XD, DIN, 384, XD*DIN, XD);
    // chunked selective scan (fused dt_proj+softplus; delta->gbuf, then g in place)
    scan_pass1<<<dim3(NCHUNK, NB*2), 384, 0, stream>>>(xc, xdbl, dtw, dtb, alog, ws2, gbuf, pi);
    scan_prefix<<<192, 256, 0, stream>>>(ws2);
    scan_pass2<<<dim3(NCHUNK, NB*2), 384, 0, stream>>>(xc, xz, xdbl, alog, dvec, ws2, gbuf, pi);
    // out_proj: N=192, K=384, z-batched over dir
    mgemm<<<dim3(NC/GBN, NM/GBM, 2), 256, 0, stream>>>(
        gbuf, 768, outw + (size_t)pi*NC*DIN, ob0, NC, NC, DIN, 384, NC*DIN, (int)BLC);
    if (layer == 0) {
      ln_res<<<NB*NL, NC, 0, stream>>>(ob0, ob1, x, nw, nb, u1);
    } else {
      add_flip<<<(int)(BLC/256), 256, 0, stream>>>(ob0, ob1, outp);
    }
  }
}